// Round 13
// baseline (64.277 us; speedup 1.0000x reference)
//
#include <hip/hip_runtime.h>

// YOLO decode = batched [255 x 5776] transpose + elementwise.
// R13: 8 streams/CU. S_TILE=16 + TPB=256 -> 16320B LDS, 8 blocks/CU,
//      32 waves/CU. 5776 = 16*361 exactly: NO partial tiles, guards gone.
//      XCD swizzle (11552 = 8*1444, 1444 = 4*361: XCD x owns batches
//      4x..4x+3) keeps the 64B-granularity boundary lines L2-shared.
//      Same conflict-free scatter / unrolled geometry / contiguous nt stores.

#define BATCH   32
#define ATTRS   85
#define CH      255
#define G_      76
#define SP      5776          // 16 * 361 exactly
#define STRIDE_F 8.0f
#define S_TILE  16
#define TPB     256
#define TILES_PER_B 361
#define NTILES  (BATCH * TILES_PER_B)   // 11552 = 8 * 1444

typedef float f4 __attribute__((ext_vector_type(4)));

__device__ __forceinline__ float decode1(float val, int attr, int s,
                                         float ax, float ay) {
    if (attr == 2) return __expf(val) * ax;
    if (attr == 3) return __expf(val) * ay;
    const float sg = __builtin_amdgcn_rcpf(1.0f + __expf(-val));
    if (attr == 0) return (sg + (float)(s % G_)) * STRIDE_F;
    if (attr == 1) return (sg + (float)(s / G_)) * STRIDE_F;
    return sg;
}

__global__ __launch_bounds__(TPB, 8) void yolo_decode_kernel(
        const float* __restrict__ pred,
        const float* __restrict__ anchors,
        float* __restrict__ out) {
    __shared__ float lds[S_TILE * CH];   // 16320 B -> 8 blocks/CU

    const int tid = threadIdx.x;

    // ---- bijective XCD swizzle ----
    const int bid = blockIdx.x;
    const int xcd = bid & 7;
    const int sub = bid >> 3;                 // 0..1443
    const int bq  = sub / TILES_PER_B;        // 0..3
    const int b   = (xcd << 2) + bq;
    const int t   = sub - bq * TILES_PER_B;
    const int s0  = t * S_TILE;

    const float a0x = anchors[0], a0y = anchors[1];
    const float a1x = anchors[2], a1y = anchors[3];
    const float a2x = anchors[4], a2y = anchors[5];

    // per-thread geometry: c0 = 4*(tid>>4)+(tid&3) in 0..63, sl in {0,4,8,12};
    // 32-lane phase banks (c - sl - e) mod 32: worst 2-way (free, m136).
    const int c0 = ((tid >> 4) << 2) | (tid & 3);   // 0..63
    const int sl = ((tid >> 2) & 3) << 2;           // 0..12
    const bool act3 = (c0 + 192) < CH;

    const int cA = c0,       aA = cA / ATTRS, atA = cA - aA * ATTRS;
    const int cB = c0 + 64,  aB = cB / ATTRS, atB = cB - aB * ATTRS;
    const int cC = c0 + 128, aC = cC / ATTRS, atC = cC - aC * ATTRS;
    const int cD = c0 + 192, aD = cD / ATTRS, atD = cD - aD * ATTRS;
    const float axA = (aA == 0) ? a0x : (aA == 1) ? a1x : a2x;
    const float ayA = (aA == 0) ? a0y : (aA == 1) ? a1y : a2y;
    const float axB = (aB == 0) ? a0x : (aB == 1) ? a1x : a2x;
    const float ayB = (aB == 0) ? a0y : (aB == 1) ? a1y : a2y;
    const float axC = (aC == 0) ? a0x : (aC == 1) ? a1x : a2x;
    const float ayC = (aC == 0) ? a0y : (aC == 1) ? a1y : a2y;
    const float axD = (aD == 0) ? a0x : (aD == 1) ? a1x : a2x;
    const float ayD = (aD == 0) ? a0y : (aD == 1) ? a1y : a2y;

    // ---- read: 4 coalesced f4 loads (no guards: no partial tiles) ----
    const float* __restrict__ src = pred + (size_t)b * ((size_t)CH * SP) + s0 + sl;
    f4 v0 = *(const f4*)(src + (size_t)cA * SP);
    f4 v1 = *(const f4*)(src + (size_t)cB * SP);
    f4 v2 = *(const f4*)(src + (size_t)cC * SP);
    f4 v3 = {0,0,0,0};
    if (act3) v3 = *(const f4*)(src + (size_t)cD * SP);

    // ---- decode -> LDS scatter ----
    #pragma unroll
    for (int e = 0; e < 4; ++e) {
        const int r = sl + e, s = s0 + r;
        lds[r * CH + cA] = decode1(v0[e], atA, s, axA, ayA);
        lds[r * CH + cB] = decode1(v1[e], atB, s, axB, ayB);
        lds[r * CH + cC] = decode1(v2[e], atC, s, axC, ayC);
        if (act3) lds[r * CH + cD] = decode1(v3[e], atD, s, axD, ayD);
    }
    __syncthreads();

    // ---- store: contiguous [16*255] floats, aligned nt f4 ----
    float* __restrict__ dst = out + (size_t)b * ((size_t)SP * CH)
                                  + (size_t)s0 * CH;
    #pragma unroll
    for (int k = 0; k < 4; ++k) {            // 1020 f4 / 256 threads, j<1020
        const int j = tid + k * TPB;
        if (j < (S_TILE * CH) / 4) {
            f4 w = *(const f4*)(lds + 4 * j);
            __builtin_nontemporal_store(w, (f4*)(dst + 4 * j));
        }
    }
}

extern "C" void kernel_launch(void* const* d_in, const int* in_sizes, int n_in,
                              void* d_out, int out_size, void* d_ws, size_t ws_size,
                              hipStream_t stream) {
    const float* pred    = (const float*)d_in[0];
    const float* anchors = (const float*)d_in[1];
    float* out = (float*)d_out;

    yolo_decode_kernel<<<NTILES, TPB, 0, stream>>>(pred, anchors, out);
}